// Round 1
// baseline (8004.352 us; speedup 1.0000x reference)
//
#include <hip/hip_runtime.h>
#include <hip/hip_bf16.h>
#include <stdint.h>

// Problem constants
#define HD   512          // hidden
#define BD   64           // batch
#define TD   512          // timesteps (S*W = 16*32)
#define ED   300          // input embed
#define EPD  320          // padded embed (mult of 32)
#define KTOT (HD + EPD)   // 832 fused K
#define NKB  (KTOT / 32)  // 26 K-blocks of 32
#define NWG  128          // 64 WGs per direction
#define JS   8            // h-columns per WG

typedef __attribute__((ext_vector_type(8))) short bf16x8;
typedef __attribute__((ext_vector_type(4))) float f32x4;

__device__ __forceinline__ float sigm_f(float x) {
    return __builtin_amdgcn_rcpf(1.0f + __expf(-x));
}
__device__ __forceinline__ float tanh_f(float x) {
    // tanh(x) = 2*sigmoid(2x) - 1
    return fmaf(2.0f, __builtin_amdgcn_rcpf(1.0f + __expf(-2.0f * x)), -1.0f);
}

// Monotone-counter grid barrier: each WG adds 1; pass when cnt >= target.
// Safe: first WG to arrive for barrier n+1 must have passed barrier n, which
// requires all 128 n-th arrivals (cnt cannot reach 128n otherwise).
__device__ __forceinline__ void gbar(unsigned* cnt, unsigned target) {
    __syncthreads();
    if (threadIdx.x == 0) {
        __threadfence();  // release h writes (agent scope)
        __hip_atomic_fetch_add(cnt, 1u, __ATOMIC_RELEASE, __HIP_MEMORY_SCOPE_AGENT);
        while (__hip_atomic_load(cnt, __ATOMIC_ACQUIRE, __HIP_MEMORY_SCOPE_AGENT) < target) {
            __builtin_amdgcn_s_sleep(2);
        }
        __threadfence();  // acquire
    }
    __syncthreads();
}

// ---- kernel 0: cast input x [B][T][300] f32 -> [B][T][320] bf16 (zero pad) ----
__global__ __launch_bounds__(256) void cast_x_kernel(const float* __restrict__ x,
                                                     __hip_bfloat16* __restrict__ xb) {
    int i = blockIdx.x * 256 + threadIdx.x;   // over BD*TD*EPD = 10485760
    int e = i % EPD;
    int bt = i / EPD;
    float v = (e < ED) ? x[bt * ED + e] : 0.0f;
    xb[i] = __float2bfloat16(v);
}

// ---- kernel 1: persistent bidirectional LSTM ----
// WG w: d = w>>6 (direction), slice = w&63, j0 = slice*8.
// Owns gate rows {q*512 + j0 + jj : q in 0..3, jj in 0..7}, interleaved so
// N-tile column c (0..15): q = c&3, jj = nt*4 + (c>>2).
__global__ __launch_bounds__(256, 1) void lstm_persistent(
    const __hip_bfloat16* __restrict__ xb,
    const float* __restrict__ wih_f, const float* __restrict__ whh_f, const float* __restrict__ bias_f,
    const float* __restrict__ wih_b, const float* __restrict__ whh_b, const float* __restrict__ bias_b,
    __hip_bfloat16* h_buf,   // [2 time-bufs][2 dir][B][H] bf16
    float* wmaxp,            // [2 dir][16 seg][B][H] f32
    unsigned* bar_cnt)
{
    __shared__ __hip_bfloat16 wlds[2][NKB][64][8];  // 53,248 B: B-fragments, frag-ordered

    const int wg = blockIdx.x;
    const int d = wg >> 6;
    const int slice = wg & 63;
    const int j0 = slice * JS;
    const int tid = threadIdx.x;
    const int lane = tid & 63;
    const int wv = tid >> 6;          // wave id = M-tile (16 batches each)
    const int c = lane & 15;          // N-column within tile
    const int q = c & 3;              // gate: 0=i 1=f 2=g~ 3=o

    const float* WHH  = d ? whh_b  : whh_f;
    const float* WIH  = d ? wih_b  : wih_f;
    const float* BIAS = d ? bias_b : bias_f;

    // --- preamble: convert weight slice (f32 -> bf16) into LDS, frag-ordered ---
    for (int slot = tid; slot < 2 * NKB * 64; slot += 256) {
        int l = slot & 63;
        int rest = slot >> 6;
        int kb = rest % NKB;
        int nt = rest / NKB;
        int cc = l & 15;
        int qq = cc & 3;
        int jj = nt * 4 + (cc >> 2);
        int gr = qq * HD + j0 + jj;          // global gate row
        int kbase = kb * 32 + ((l >> 4) << 3);
        __hip_bfloat16 tmp[8];
        #pragma unroll
        for (int e = 0; e < 8; ++e) {
            int k = kbase + e;
            float v;
            if (k < HD) v = WHH[gr * HD + k];
            else {
                int ke = k - HD;
                v = (ke < ED) ? WIH[gr * ED + ke] : 0.0f;
            }
            tmp[e] = __float2bfloat16(v);
        }
        *reinterpret_cast<bf16x8*>(&wlds[nt][kb][l][0]) = *reinterpret_cast<bf16x8*>(tmp);
    }

    // per-lane bias for each N-tile (depends only on column c)
    float bias_nt[2];
    #pragma unroll
    for (int nt = 0; nt < 2; ++nt) {
        int jj = nt * 4 + (c >> 2);
        bias_nt[nt] = BIAS[q * HD + j0 + jj];
    }

    // zero our slice of h time-buffer 0
    for (int s = tid; s < BD * JS; s += 256) {
        int b = s >> 3, jj = s & 7;
        h_buf[(0 * 2 + d) * (BD * HD) + b * HD + j0 + jj] = __float2bfloat16(0.0f);
    }

    // recurrent state (owner lanes q==0 hold the authoritative copy)
    float c_st[2][4] = {{0.f, 0.f, 0.f, 0.f}, {0.f, 0.f, 0.f, 0.f}};
    float wm[2][4];
    #pragma unroll
    for (int nt = 0; nt < 2; ++nt)
        #pragma unroll
        for (int r = 0; r < 4; ++r) wm[nt][r] = -3.0e38f;

    gbar(bar_cnt, NWG);  // barrier 0: weights + h0 visible

    const int arow = (wv << 4) + c;               // A-fragment batch row (input layout)
    const int koff = (lane >> 4) << 3;            // 0,8,16,24
    const int rowbase = (wv << 4) + ((lane >> 4) << 2);  // C-fragment batch base (output layout)

    for (int t = 0; t < TD; ++t) {
        const int te = d ? (TD - 1 - t) : t;
        const __hip_bfloat16* hin = h_buf + ((t & 1) * 2 + d) * (BD * HD);
        const __hip_bfloat16* hrow = hin + arow * HD + koff;
        const __hip_bfloat16* xrow = xb + (arow * TD + te) * EPD + koff;

        f32x4 acc0 = {0.f, 0.f, 0.f, 0.f};
        f32x4 acc1 = {0.f, 0.f, 0.f, 0.f};

        #pragma unroll
        for (int kb = 0; kb < NKB; ++kb) {
            bf16x8 afrag;
            if (kb < 16) afrag = *reinterpret_cast<const bf16x8*>(hrow + kb * 32);
            else         afrag = *reinterpret_cast<const bf16x8*>(xrow + (kb - 16) * 32);
            bf16x8 b0 = *reinterpret_cast<const bf16x8*>(&wlds[0][kb][lane][0]);
            bf16x8 b1 = *reinterpret_cast<const bf16x8*>(&wlds[1][kb][lane][0]);
            acc0 = __builtin_amdgcn_mfma_f32_16x16x32_bf16(afrag, b0, acc0, 0, 0, 0);
            acc1 = __builtin_amdgcn_mfma_f32_16x16x32_bf16(afrag, b1, acc1, 0, 0, 0);
        }

        // activations: each lane activates its own gate column
        float aown[2][4];
        #pragma unroll
        for (int nt = 0; nt < 2; ++nt) {
            #pragma unroll
            for (int r = 0; r < 4; ++r) {
                float v = (nt ? acc1[r] : acc0[r]) + bias_nt[nt];
                aown[nt][r] = (q == 2) ? tanh_f(v) : sigm_f(v);
            }
        }
        // gather f (c^1), g~ (c^2), o (c^3) to owner lanes (q==0)
        float gf[2][4], gg[2][4], go[2][4];
        #pragma unroll
        for (int nt = 0; nt < 2; ++nt) {
            #pragma unroll
            for (int r = 0; r < 4; ++r) {
                gf[nt][r] = __shfl_xor(aown[nt][r], 1, 64);
                gg[nt][r] = __shfl_xor(aown[nt][r], 2, 64);
                go[nt][r] = __shfl_xor(aown[nt][r], 3, 64);
            }
        }

        __hip_bfloat16* hout = h_buf + (((t + 1) & 1) * 2 + d) * (BD * HD);
        if (q == 0) {
            #pragma unroll
            for (int nt = 0; nt < 2; ++nt) {
                int jj = (nt << 2) + (c >> 2);
                #pragma unroll
                for (int r = 0; r < 4; ++r) {
                    float iv = aown[nt][r], fv = gf[nt][r], gv = gg[nt][r], ov = go[nt][r];
                    float cn = fmaf(fv, c_st[nt][r], iv * gv);
                    c_st[nt][r] = cn;
                    float hn = ov * tanh_f(cn);
                    wm[nt][r] = fmaxf(wm[nt][r], hn);
                    hout[(rowbase + r) * HD + j0 + jj] = __float2bfloat16(hn);
                }
            }
            if ((t & 31) == 31) {
                int seg = t >> 5;
                if (d) seg = 15 - seg;
                #pragma unroll
                for (int nt = 0; nt < 2; ++nt) {
                    int jj = (nt << 2) + (c >> 2);
                    #pragma unroll
                    for (int r = 0; r < 4; ++r) {
                        wmaxp[((d * 16 + seg) * BD + rowbase + r) * HD + j0 + jj] = wm[nt][r];
                        wm[nt][r] = -3.0e38f;
                    }
                }
            }
        }

        gbar(bar_cnt, (unsigned)(t + 2) * NWG);
    }
}

// ---- kernel 2: window-max sum, segment max, decode ----
__global__ __launch_bounds__(256) void pool_decode(const float* __restrict__ wmaxp,
                                                   const float* __restrict__ wdec,
                                                   const float* __restrict__ bdec,
                                                   float* __restrict__ out) {
    __shared__ float red[4 * 256];
    int b = blockIdx.x;
    int tid = threadIdx.x;
    float p[4] = {0.f, 0.f, 0.f, 0.f};
    for (int j = tid; j < HD; j += 256) {
        float m = -3.0e38f;
        #pragma unroll
        for (int s = 0; s < 16; ++s) {
            float v = wmaxp[((0 * 16 + s) * BD + b) * HD + j] +
                      wmaxp[((1 * 16 + s) * BD + b) * HD + j];
            m = fmaxf(m, v);
        }
        m = fmaxf(m, 0.0f);  // relu
        #pragma unroll
        for (int q2 = 0; q2 < 4; ++q2) p[q2] = fmaf(m, wdec[q2 * HD + j], p[q2]);
    }
    #pragma unroll
    for (int q2 = 0; q2 < 4; ++q2) red[q2 * 256 + tid] = p[q2];
    __syncthreads();
    for (int off = 128; off > 0; off >>= 1) {
        if (tid < off) {
            #pragma unroll
            for (int q2 = 0; q2 < 4; ++q2) red[q2 * 256 + tid] += red[q2 * 256 + tid + off];
        }
        __syncthreads();
    }
    if (tid < 4) {
        float logit = red[tid * 256] + bdec[tid];
        out[b * 4 + tid] = sigm_f(logit);
    }
}

extern "C" void kernel_launch(void* const* d_in, const int* in_sizes, int n_in,
                              void* d_out, int out_size, void* d_ws, size_t ws_size,
                              hipStream_t stream) {
    (void)in_sizes; (void)n_in; (void)out_size; (void)ws_size;
    const float* x     = (const float*)d_in[0];
    const float* wih_f = (const float*)d_in[1];
    const float* whh_f = (const float*)d_in[2];
    const float* b_f   = (const float*)d_in[3];
    const float* wih_b = (const float*)d_in[4];
    const float* whh_b = (const float*)d_in[5];
    const float* b_b   = (const float*)d_in[6];
    const float* wdec  = (const float*)d_in[7];
    const float* bdec  = (const float*)d_in[8];

    char* ws = (char*)d_ws;
    unsigned* bar = (unsigned*)ws;                          // 256 B barrier area
    __hip_bfloat16* xb = (__hip_bfloat16*)(ws + 256);       // BD*TD*EPD*2 = 20,971,520 B
    size_t off = 256 + (size_t)BD * TD * EPD * 2;
    __hip_bfloat16* hbuf = (__hip_bfloat16*)(ws + off);     // 2*2*BD*HD*2 = 262,144 B
    off += (size_t)2 * 2 * BD * HD * 2;
    float* wmaxp = (float*)(ws + off);                      // 2*16*BD*HD*4 = 4,194,304 B

    hipMemsetAsync(bar, 0, 256, stream);
    cast_x_kernel<<<dim3((BD * TD * EPD) / 256), dim3(256), 0, stream>>>(x, xb);

    const __hip_bfloat16* xb_c = xb;
    __hip_bfloat16* hbuf_p = hbuf;
    float* wmax_p = wmaxp;
    unsigned* bar_p = bar;
    void* args[] = {(void*)&xb_c, (void*)&wih_f, (void*)&whh_f, (void*)&b_f,
                    (void*)&wih_b, (void*)&whh_b, (void*)&b_b,
                    (void*)&hbuf_p, (void*)&wmax_p, (void*)&bar_p};
    hipLaunchCooperativeKernel((void*)lstm_persistent, dim3(NWG), dim3(256), args, 0, stream);

    pool_decode<<<dim3(BD), dim3(256), 0, stream>>>(wmaxp, wdec, bdec, (float*)d_out);
}

// Round 2
// 6128.917 us; speedup vs baseline: 1.3060x; 1.3060x over previous
//
#include <hip/hip_runtime.h>
#include <hip/hip_bf16.h>
#include <stdint.h>
#include <string.h>

// Problem constants
#define HD   512          // hidden
#define BD   64           // batch
#define TD   512          // timesteps (S*W = 16*32)
#define ED   300          // input embed
#define EPD  320          // padded embed (mult of 32)
#define NKB  26           // fused K blocks of 32: 16 (h) + 10 (x)
#define NWG  128          // total WGs
#define NWGD 64           // WGs per direction
#define JS   8            // h-columns per WG
#define NT   2            // 16-wide N-tiles per WG (JS*4 gates / 16)

typedef __attribute__((ext_vector_type(8))) short bf16x8;
typedef __attribute__((ext_vector_type(4))) float f32x4;

__device__ __forceinline__ float sigm_f(float x) {
    return __builtin_amdgcn_rcpf(1.0f + __expf(-x));
}
__device__ __forceinline__ float tanh_f(float x) {
    return fmaf(2.0f, __builtin_amdgcn_rcpf(1.0f + __expf(-2.0f * x)), -1.0f);
}
__device__ __forceinline__ unsigned bf16bits(float v) {
    __hip_bfloat16 b = __float2bfloat16(v);
    unsigned short u;
    memcpy(&u, &b, 2);
    return (unsigned)u;
}

// 16B h-fragment load, agent scope (sc1: bypasses stale per-XCD L2, reads MALL)
union HU { unsigned long long u[2]; bf16x8 v; };
__device__ __forceinline__ bf16x8 ld_h16(const __hip_bfloat16* p) {
    HU r;
    const unsigned long long* q = (const unsigned long long*)p;
    r.u[0] = __hip_atomic_load(q,     __ATOMIC_RELAXED, __HIP_MEMORY_SCOPE_AGENT);
    r.u[1] = __hip_atomic_load(q + 1, __ATOMIC_RELAXED, __HIP_MEMORY_SCOPE_AGENT);
    return r.v;
}
// u32 (2 bf16) agent-scope write-through store
__device__ __forceinline__ void st_h32(__hip_bfloat16* p, unsigned u) {
    __hip_atomic_store((unsigned*)p, u, __ATOMIC_RELAXED, __HIP_MEMORY_SCOPE_AGENT);
}

// ---- kernel 0: cast input x [B][T][300] f32 -> [B][T][320] bf16 (zero pad) ----
__global__ __launch_bounds__(256) void cast_x_kernel(const float* __restrict__ x,
                                                     __hip_bfloat16* __restrict__ xb) {
    int i = blockIdx.x * 256 + threadIdx.x;
    int e = i % EPD;
    int bt = i / EPD;
    float v = (e < ED) ? x[bt * ED + e] : 0.0f;
    xb[i] = __float2bfloat16(v);
}

// ---- kernel 1: persistent bidirectional LSTM ----
__global__ __launch_bounds__(256, 1) void lstm_persistent(
    const __hip_bfloat16* __restrict__ xb,
    const float* __restrict__ wih_f, const float* __restrict__ whh_f, const float* __restrict__ bias_f,
    const float* __restrict__ wih_b, const float* __restrict__ whh_b, const float* __restrict__ bias_b,
    __hip_bfloat16* h_buf,   // [2 time-bufs][2 dir][B][H] bf16
    float* wmaxp,            // [2 dir][16 seg][B][H] f32
    unsigned* bar)           // 16 counter lines x 128B
{
    __shared__ __hip_bfloat16 wlds[NT][NKB][64][8];  // 53,248 B

    const int wg = blockIdx.x;
    const int d = wg >> 6;
    const int slice = wg & 63;
    const int j0 = slice * JS;
    const int tid = threadIdx.x;
    const int lane = tid & 63;
    const int wv = tid >> 6;
    const int mw = wv & 1;        // M-pair: batches mw*32 .. mw*32+31
    const int nw = wv >> 1;       // N-tile id (0..1)
    const int c = lane & 15;      // column within 16-wide tile
    const int q = c & 3;          // gate: 0=i 1=f 2=g~ 3=o
    const int g16 = lane >> 4;    // 0..3

    const float* WHH  = d ? whh_b  : whh_f;
    const float* WIH  = d ? wih_b  : wih_f;
    const float* BIAS = d ? bias_b : bias_f;

    // --- weights (f32 -> bf16) into LDS, B-fragment-ordered ---
    for (int slot = tid; slot < NT * NKB * 64; slot += 256) {
        int l = slot & 63;
        int rest = slot >> 6;
        int kb = rest % NKB;
        int nt = rest / NKB;
        int cc = l & 15;
        int qq = cc & 3;
        int jj = nt * 4 + (cc >> 2);
        int gr = qq * HD + j0 + jj;
        int kbase = kb * 32 + ((l >> 4) << 3);
        __hip_bfloat16 tmp[8];
        #pragma unroll
        for (int e = 0; e < 8; ++e) {
            int k = kbase + e;
            float v;
            if (k < HD) v = WHH[gr * HD + k];
            else {
                int ke = k - HD;
                v = (ke < ED) ? WIH[gr * ED + ke] : 0.0f;
            }
            tmp[e] = __float2bfloat16(v);
        }
        *reinterpret_cast<bf16x8*>(&wlds[nt][kb][l][0]) = *reinterpret_cast<bf16x8*>(tmp);
    }

    const float bias_n = BIAS[q * HD + j0 + nw * 4 + (c >> 2)];

    // --- h0 = 0 for our slice (sc1 stores so consumers' sc1 loads see it) ---
    {
        __hip_bfloat16* h0 = h_buf + (0 * 2 + d) * (BD * HD);
        for (int s = tid; s < BD * (JS / 2); s += 256) {
            int b = s >> 2, jp = s & 3;
            st_h32(h0 + b * HD + j0 + jp * 2, 0u);
        }
    }

    unsigned* my_line   = bar + (d * 8 + (slice & 7)) * 32;  // 128B apart
    unsigned* dir_lines = bar + d * 8 * 32;

    // arrive: drain our sc1 stores to MALL, then one add on our line
    #define ARRIVE() do { \
        asm volatile("s_waitcnt vmcnt(0)" ::: "memory"); \
        __syncthreads(); \
        if (tid == 0) __hip_atomic_fetch_add(my_line, 1u, __ATOMIC_RELAXED, __HIP_MEMORY_SCOPE_AGENT); \
    } while (0)
    #define WAITFOR(target) do { \
        if (tid == 0) { \
            for (;;) { \
                unsigned s_ = 0; \
                _Pragma("unroll") \
                for (int i_ = 0; i_ < 8; ++i_) \
                    s_ += __hip_atomic_load(dir_lines + i_ * 32, __ATOMIC_RELAXED, __HIP_MEMORY_SCOPE_AGENT); \
                if (s_ >= (target)) break; \
                __builtin_amdgcn_s_sleep(1); \
            } \
        } \
        __syncthreads(); \
    } while (0)

    ARRIVE();   // barrier 0: h0 visible; per-dir sum -> 64

    const int batchA = mw * 32 + c;
    const int batchB = batchA + 16;
    const int koff = g16 << 3;
    const int rb0 = mw * 32 + (g16 << 2);   // + mt*16 + r

    float c_st[2][4] = {{0.f,0.f,0.f,0.f},{0.f,0.f,0.f,0.f}};
    float wm[2][4];
    #pragma unroll
    for (int mt = 0; mt < 2; ++mt)
        #pragma unroll
        for (int r = 0; r < 4; ++r) wm[mt][r] = -3.0e38f;

    // prologue: x-part accumulators for t=0
    f32x4 ax0 = {0.f,0.f,0.f,0.f}, ax1 = {0.f,0.f,0.f,0.f};
    {
        int te = d ? (TD - 1) : 0;
        const __hip_bfloat16* xrA = xb + ((size_t)batchA * TD + te) * EPD + koff;
        const __hip_bfloat16* xrB = xb + ((size_t)batchB * TD + te) * EPD + koff;
        #pragma unroll
        for (int kb = 0; kb < 10; ++kb) {
            bf16x8 aA = *reinterpret_cast<const bf16x8*>(xrA + kb * 32);
            bf16x8 aB = *reinterpret_cast<const bf16x8*>(xrB + kb * 32);
            bf16x8 b  = *reinterpret_cast<const bf16x8*>(&wlds[nw][16 + kb][lane][0]);
            ax0 = __builtin_amdgcn_mfma_f32_16x16x32_bf16(aA, b, ax0, 0, 0, 0);
            ax1 = __builtin_amdgcn_mfma_f32_16x16x32_bf16(aB, b, ax1, 0, 0, 0);
        }
    }

    for (int t = 0; t < TD; ++t) {
        WAITFOR((unsigned)(t + 1) * NWGD);

        const __hip_bfloat16* hin = h_buf + ((t & 1) * 2 + d) * (BD * HD);
        const __hip_bfloat16* hrA = hin + batchA * HD + koff;
        const __hip_bfloat16* hrB = hin + batchB * HD + koff;

        f32x4 acc0 = ax0, acc1 = ax1;
        #pragma unroll
        for (int kb = 0; kb < 16; ++kb) {
            bf16x8 aA = ld_h16(hrA + kb * 32);
            bf16x8 aB = ld_h16(hrB + kb * 32);
            bf16x8 b  = *reinterpret_cast<const bf16x8*>(&wlds[nw][kb][lane][0]);
            acc0 = __builtin_amdgcn_mfma_f32_16x16x32_bf16(aA, b, acc0, 0, 0, 0);
            acc1 = __builtin_amdgcn_mfma_f32_16x16x32_bf16(aB, b, acc1, 0, 0, 0);
        }

        // activations (each lane activates its own gate column)
        float aown[2][4];
        #pragma unroll
        for (int mt = 0; mt < 2; ++mt)
            #pragma unroll
            for (int r = 0; r < 4; ++r) {
                float v = (mt ? acc1[r] : acc0[r]) + bias_n;
                aown[mt][r] = (q == 2) ? tanh_f(v) : sigm_f(v);
            }
        // gather f,g,o to owner lanes (q==0)
        float gf[2][4], gg[2][4], go[2][4];
        #pragma unroll
        for (int mt = 0; mt < 2; ++mt)
            #pragma unroll
            for (int r = 0; r < 4; ++r) {
                gf[mt][r] = __shfl_xor(aown[mt][r], 1, 64);
                gg[mt][r] = __shfl_xor(aown[mt][r], 2, 64);
                go[mt][r] = __shfl_xor(aown[mt][r], 3, 64);
            }

        __hip_bfloat16* hout = h_buf + (((t + 1) & 1) * 2 + d) * (BD * HD);
        if (q == 0) {
            #pragma unroll
            for (int mt = 0; mt < 2; ++mt) {
                #pragma unroll
                for (int r = 0; r < 4; ++r) {
                    float iv = aown[mt][r], fv = gf[mt][r], gv = gg[mt][r], ov = go[mt][r];
                    float cn = fmaf(fv, c_st[mt][r], iv * gv);
                    c_st[mt][r] = cn;
                    float hn = ov * tanh_f(cn);
                    wm[mt][r] = fmaxf(wm[mt][r], hn);
                    // pack col pair (lane c with partner c^4), lanes c in {0,8} store u32
                    float hp = __shfl_xor(hn, 4, 64);
                    if ((c & 4) == 0) {
                        unsigned u = bf16bits(hn) | (bf16bits(hp) << 16);
                        int row = rb0 + mt * 16 + r;
                        st_h32(hout + row * HD + j0 + nw * 4 + (c >> 2), u);
                    }
                }
            }
        }

        ARRIVE();   // per-dir sum -> 64*(t+2)

        // off-critical-path bookkeeping
        if (q == 0 && (t & 31) == 31) {
            int seg = t >> 5;
            if (d) seg = 15 - seg;
            int jjown = nw * 4 + (c >> 2);
            #pragma unroll
            for (int mt = 0; mt < 2; ++mt)
                #pragma unroll
                for (int r = 0; r < 4; ++r) {
                    int row = rb0 + mt * 16 + r;
                    wmaxp[((d * 16 + seg) * BD + row) * HD + j0 + jjown] = wm[mt][r];
                    wm[mt][r] = -3.0e38f;
                }
        }

        // pipelined x-part for t+1 (independent of h_{t+1})
        if (t + 1 < TD) {
            int te = d ? (TD - 2 - t) : (t + 1);
            const __hip_bfloat16* xrA = xb + ((size_t)batchA * TD + te) * EPD + koff;
            const __hip_bfloat16* xrB = xb + ((size_t)batchB * TD + te) * EPD + koff;
            f32x4 nx0 = {0.f,0.f,0.f,0.f}, nx1 = {0.f,0.f,0.f,0.f};
            #pragma unroll
            for (int kb = 0; kb < 10; ++kb) {
                bf16x8 aA = *reinterpret_cast<const bf16x8*>(xrA + kb * 32);
                bf16x8 aB = *reinterpret_cast<const bf16x8*>(xrB + kb * 32);
                bf16x8 b  = *reinterpret_cast<const bf16x8*>(&wlds[nw][16 + kb][lane][0]);
                nx0 = __builtin_amdgcn_mfma_f32_16x16x32_bf16(aA, b, nx0, 0, 0, 0);
                nx1 = __builtin_amdgcn_mfma_f32_16x16x32_bf16(aB, b, nx1, 0, 0, 0);
            }
            ax0 = nx0; ax1 = nx1;
        }
    }
    #undef ARRIVE
    #undef WAITFOR
}

// ---- kernel 2: window-max sum, segment max, decode ----
__global__ __launch_bounds__(256) void pool_decode(const float* __restrict__ wmaxp,
                                                   const float* __restrict__ wdec,
                                                   const float* __restrict__ bdec,
                                                   float* __restrict__ out) {
    __shared__ float red[4 * 256];
    int b = blockIdx.x;
    int tid = threadIdx.x;
    float p[4] = {0.f, 0.f, 0.f, 0.f};
    for (int j = tid; j < HD; j += 256) {
        float m = -3.0e38f;
        #pragma unroll
        for (int s = 0; s < 16; ++s) {
            float v = wmaxp[((0 * 16 + s) * BD + b) * HD + j] +
                      wmaxp[((1 * 16 + s) * BD + b) * HD + j];
            m = fmaxf(m, v);
        }
        m = fmaxf(m, 0.0f);
        #pragma unroll
        for (int q2 = 0; q2 < 4; ++q2) p[q2] = fmaf(m, wdec[q2 * HD + j], p[q2]);
    }
    #pragma unroll
    for (int q2 = 0; q2 < 4; ++q2) red[q2 * 256 + tid] = p[q2];
    __syncthreads();
    for (int off = 128; off > 0; off >>= 1) {
        if (tid < off) {
            #pragma unroll
            for (int q2 = 0; q2 < 4; ++q2) red[q2 * 256 + tid] += red[q2 * 256 + tid + off];
        }
        __syncthreads();
    }
    if (tid < 4) {
        float logit = red[tid * 256] + bdec[tid];
        out[b * 4 + tid] = sigm_f(logit);
    }
}

extern "C" void kernel_launch(void* const* d_in, const int* in_sizes, int n_in,
                              void* d_out, int out_size, void* d_ws, size_t ws_size,
                              hipStream_t stream) {
    (void)in_sizes; (void)n_in; (void)out_size; (void)ws_size;
    const float* x     = (const float*)d_in[0];
    const float* wih_f = (const float*)d_in[1];
    const float* whh_f = (const float*)d_in[2];
    const float* b_f   = (const float*)d_in[3];
    const float* wih_b = (const float*)d_in[4];
    const float* whh_b = (const float*)d_in[5];
    const float* b_b   = (const float*)d_in[6];
    const float* wdec  = (const float*)d_in[7];
    const float* bdec  = (const float*)d_in[8];

    char* ws = (char*)d_ws;
    unsigned* bar = (unsigned*)ws;                           // 2048 B: 16 lines x 128B
    __hip_bfloat16* xb = (__hip_bfloat16*)(ws + 2048);       // BD*TD*EPD*2 = 20,971,520 B
    size_t off = 2048 + (size_t)BD * TD * EPD * 2;
    __hip_bfloat16* hbuf = (__hip_bfloat16*)(ws + off);      // 2*2*BD*HD*2 = 262,144 B
    off += (size_t)2 * 2 * BD * HD * 2;
    float* wmaxp = (float*)(ws + off);                       // 2*16*BD*HD*4 = 4,194,304 B

    hipMemsetAsync(bar, 0, 2048, stream);
    cast_x_kernel<<<dim3((BD * TD * EPD) / 256), dim3(256), 0, stream>>>(x, xb);

    const __hip_bfloat16* xb_c = xb;
    __hip_bfloat16* hbuf_p = hbuf;
    float* wmax_p = wmaxp;
    unsigned* bar_p = bar;
    void* args[] = {(void*)&xb_c, (void*)&wih_f, (void*)&whh_f, (void*)&b_f,
                    (void*)&wih_b, (void*)&whh_b, (void*)&b_b,
                    (void*)&hbuf_p, (void*)&wmax_p, (void*)&bar_p};
    hipLaunchCooperativeKernel((void*)lstm_persistent, dim3(NWG), dim3(256), args, 0, stream);

    pool_decode<<<dim3(BD), dim3(256), 0, stream>>>(wmaxp, wdec, bdec, (float*)d_out);
}